// Round 1
// baseline (321.003 us; speedup 1.0000x reference)
//
#include <hip/hip_runtime.h>
#include <hip/hip_bf16.h>
#include <math.h>

#define D_MODEL 768
#define NHEADS  12
#define DHEAD   64
#define NQR     8     // query rows
#define BB      16    // batch (ranks)
#define PP      197   // tokens per rank
#define NPAIR   256   // BB*BB
#define MKV     (BB*PP)     // 3152
#define MOUT    (NPAIR*NQR) // 2048
#define LN_EPSF 1e-5f
#define SCALEF  0.125f      // 64^-0.5

// ---------------------------------------------------------------------------
// q path: q_ln = LN(q_x @ q_w.T + q_b) * lnq_w + lnq_b   (8 rows, tiny)
// ---------------------------------------------------------------------------
__global__ __launch_bounds__(256) void qpath_kernel(
    const float* __restrict__ qx, const float* __restrict__ qw,
    const float* __restrict__ qb, const float* __restrict__ lnw,
    const float* __restrict__ lnb, float* __restrict__ qln)
{
  __shared__ float xrow[D_MODEL];
  __shared__ float yrow[D_MODEL];
  __shared__ float red[256], red2[256];
  int r = blockIdx.x, tid = threadIdx.x;
  for (int c = tid; c < D_MODEL; c += 256) xrow[c] = qx[r*D_MODEL + c];
  __syncthreads();
  for (int c = tid; c < D_MODEL; c += 256) {
    const float* wr = qw + (size_t)c*D_MODEL;
    float acc = 0.f;
    #pragma unroll 8
    for (int k = 0; k < D_MODEL; k++) acc += xrow[k]*wr[k];
    yrow[c] = acc + qb[c];
  }
  __syncthreads();
  float s1 = 0.f, s2 = 0.f;
  for (int c = tid; c < D_MODEL; c += 256){ float v = yrow[c]; s1 += v; s2 += v*v; }
  red[tid] = s1; red2[tid] = s2; __syncthreads();
  for (int st = 128; st > 0; st >>= 1){
    if (tid < st){ red[tid] += red[tid+st]; red2[tid] += red2[tid+st]; }
    __syncthreads();
  }
  float mean = red[0]*(1.f/D_MODEL);
  float var  = red2[0]*(1.f/D_MODEL) - mean*mean;
  float inv  = rsqrtf(var + LN_EPSF);
  for (int c = tid; c < D_MODEL; c += 256)
    qln[r*D_MODEL + c] = (yrow[c]-mean)*inv*lnw[c] + lnb[c];
}

// ---------------------------------------------------------------------------
// Tiled f32 GEMM: C[M,N] = A[M,K] @ W[N,K]^T (+ bias).  64x64 tile, BK=16,
// 256 threads, 4x4 micro-tile.  LDS stored k-major with +4 pad (stride 68:
// keeps ds_read_b128 16B-aligned, breaks the 64-stride bank collision).
// ---------------------------------------------------------------------------
__global__ __launch_bounds__(256) void gemm_nt_kernel(
    const float* __restrict__ A, const float* __restrict__ W,
    const float* __restrict__ bias, float* __restrict__ C,
    int M, int N, int K)
{
  __shared__ __align__(16) float As[16][68];
  __shared__ __align__(16) float Bs[16][68];
  int tid = threadIdx.x;
  int m0 = blockIdx.x*64, n0 = blockIdx.y*64;
  int tx = tid & 15, ty = tid >> 4;
  int lrow = tid >> 2, lk = (tid & 3) << 2;
  float acc[4][4] = {};
  const float* aptr = A + (size_t)(m0 + lrow)*K + lk;
  const float* bptr = W + (size_t)(n0 + lrow)*K + lk;
  bool avalid = (m0 + lrow) < M;
  for (int kt = 0; kt < K; kt += 16){
    float4 av = avalid ? *(const float4*)(aptr + kt) : make_float4(0.f,0.f,0.f,0.f);
    float4 bv = *(const float4*)(bptr + kt);
    __syncthreads();
    As[lk+0][lrow] = av.x; As[lk+1][lrow] = av.y;
    As[lk+2][lrow] = av.z; As[lk+3][lrow] = av.w;
    Bs[lk+0][lrow] = bv.x; Bs[lk+1][lrow] = bv.y;
    Bs[lk+2][lrow] = bv.z; Bs[lk+3][lrow] = bv.w;
    __syncthreads();
    #pragma unroll
    for (int k = 0; k < 16; k++){
      float4 a4 = *(const float4*)&As[k][ty<<2];
      float4 b4 = *(const float4*)&Bs[k][tx<<2];
      float ar[4] = {a4.x, a4.y, a4.z, a4.w};
      float br[4] = {b4.x, b4.y, b4.z, b4.w};
      #pragma unroll
      for (int r = 0; r < 4; r++)
        #pragma unroll
        for (int c = 0; c < 4; c++)
          acc[r][c] += ar[r]*br[c];
    }
  }
  float4 bb4 = bias ? *(const float4*)&bias[n0 + (tx<<2)] : make_float4(0.f,0.f,0.f,0.f);
  float bvals[4] = {bb4.x, bb4.y, bb4.z, bb4.w};
  for (int r = 0; r < 4; r++){
    int m = m0 + (ty<<2) + r;
    if (m < M){
      float4 o = make_float4(acc[r][0]+bvals[0], acc[r][1]+bvals[1],
                             acc[r][2]+bvals[2], acc[r][3]+bvals[3]);
      *(float4*)&C[(size_t)m*N + n0 + (tx<<2)] = o;
    }
  }
}

// ---------------------------------------------------------------------------
// Per-row LN with bias: out[r,:] = LN(Y[r,:] + bias) * lnw + lnb
// ---------------------------------------------------------------------------
__global__ __launch_bounds__(256) void ln_rows_kernel(
    const float* __restrict__ Y, const float* __restrict__ bias,
    const float* __restrict__ lnw, const float* __restrict__ lnb,
    float* __restrict__ out)
{
  __shared__ float red[256], red2[256];
  int r = blockIdx.x, tid = threadIdx.x;
  const float* yr = Y + (size_t)r*D_MODEL;
  float x0 = yr[tid      ] + bias[tid      ];
  float x1 = yr[tid + 256] + bias[tid + 256];
  float x2 = yr[tid + 512] + bias[tid + 512];
  red[tid] = x0 + x1 + x2; red2[tid] = x0*x0 + x1*x1 + x2*x2;
  __syncthreads();
  for (int st = 128; st > 0; st >>= 1){
    if (tid < st){ red[tid] += red[tid+st]; red2[tid] += red2[tid+st]; }
    __syncthreads();
  }
  float mean = red[0]*(1.f/768.f);
  float var  = red2[0]*(1.f/768.f) - mean*mean;
  float inv  = rsqrtf(var + LN_EPSF);
  float* orow = out + (size_t)r*D_MODEL;
  orow[tid      ] = (x0-mean)*inv*lnw[tid      ] + lnb[tid      ];
  orow[tid + 256] = (x1-mean)*inv*lnw[tid + 256] + lnb[tid + 256];
  orow[tid + 512] = (x2-mean)*inv*lnw[tid + 512] + lnb[tid + 512];
}

// ---------------------------------------------------------------------------
// Per-(rank, head, half) attention partials.
//   A[p,d] = kv_ln[r,p,h,d] + pos[half*197+p, h,d]   (197x64, LDS, stride 65)
//   s[q,p] = SCALE * <q_ln[q,h,:], A[p,:]>
//   m = max_p s;  Z = sum_p exp(s-m);  U[d] = sum_p exp(s-m) * A[p,d]
// Block: 256 threads = 8 q-groups x 32 lanes.  16x12x2 = 384 blocks.
// ---------------------------------------------------------------------------
__global__ __launch_bounds__(256) void rank_partials_kernel(
    const float* __restrict__ kv_ln, const float* __restrict__ q_ln,
    const float* __restrict__ ppe,
    float* __restrict__ m1O, float* __restrict__ z1O, float* __restrict__ u1O,
    float* __restrict__ m2O, float* __restrict__ z2O, float* __restrict__ u2O)
{
  __shared__ float A[PP*65];     // 197x64 padded to stride 65 (bank spread)
  __shared__ float qs[NQR*64];
  __shared__ float E[NQR*PP];
  int r = blockIdx.x, h = blockIdx.y, half = blockIdx.z;
  int tid = threadIdx.x;

  for (int e = tid; e < NQR*64; e += 256){
    int q = e >> 6, d = e & 63;
    qs[e] = q_ln[q*D_MODEL + h*64 + d];
  }
  for (int e = tid; e < PP*64; e += 256){
    int p = e >> 6, d = e & 63;
    A[p*65 + d] = kv_ln[((size_t)(r*PP + p))*D_MODEL + h*64 + d]
                + ppe[((size_t)(half*PP + p))*D_MODEL + h*64 + d];
  }
  __syncthreads();

  int q = tid >> 5, sub = tid & 31;
  float s[7];
  #pragma unroll
  for (int i = 0; i < 7; i++) s[i] = 0.f;
  for (int d = 0; d < 64; d++){
    float qv = qs[q*64 + d];
    #pragma unroll
    for (int i = 0; i < 7; i++){
      int p = sub + 32*i;
      int pc = p < PP ? p : PP-1;     // clamped read; overwritten below
      s[i] += qv * A[pc*65 + d];
    }
  }
  float mloc = -1e30f;
  #pragma unroll
  for (int i = 0; i < 7; i++){
    int p = sub + 32*i;
    s[i] = (p < PP) ? s[i]*SCALEF : -1e30f;
    mloc = fmaxf(mloc, s[i]);
  }
  for (int off = 16; off >= 1; off >>= 1)
    mloc = fmaxf(mloc, __shfl_xor(mloc, off, 32));
  float zloc = 0.f;
  #pragma unroll
  for (int i = 0; i < 7; i++){
    int p = sub + 32*i;
    float e = __expf(s[i] - mloc);
    if (p < PP){ E[q*PP + p] = e; zloc += e; }
  }
  for (int off = 16; off >= 1; off >>= 1)
    zloc += __shfl_xor(zloc, off, 32);

  int idx = (r*NHEADS + h)*NQR + q;
  float* mO = half ? m2O : m1O;
  float* zO = half ? z2O : z1O;
  float* uO = half ? u2O : u1O;
  if (sub == 0){ mO[idx] = mloc; zO[idx] = zloc; }
  __syncthreads();

  float u0 = 0.f, u1 = 0.f;
  for (int p = 0; p < PP; p++){
    float e = E[q*PP + p];
    u0 += e * A[p*65 + sub];
    u1 += e * A[p*65 + sub + 32];
  }
  uO[(size_t)idx*64 + sub]      = u0;
  uO[(size_t)idx*64 + sub + 32] = u1;
}

// ---------------------------------------------------------------------------
// Pair combine: values[(i*16+j)*8+q, h*64+d] =
//   (a1*U1[i,h,q,d] - a2*U2[j,h,q,d]) / (a1*Z1[i,h,q] + a2*Z2[j,h,q]),
//   a1 = exp(m1-mm), a2 = exp(m2-mm), mm = max(m1, m2)
// ---------------------------------------------------------------------------
__global__ __launch_bounds__(256) void combine_kernel(
    const float* __restrict__ m1, const float* __restrict__ z1,
    const float* __restrict__ u1, const float* __restrict__ m2,
    const float* __restrict__ z2, const float* __restrict__ u2,
    float* __restrict__ values)
{
  int pair = blockIdx.x, q = blockIdx.y, tid = threadIdx.x;
  int i = pair >> 4, j = pair & 15;
  float* vrow = values + ((size_t)(pair*NQR + q))*D_MODEL;
  for (int c = tid; c < D_MODEL; c += 256){
    int h = c >> 6, d = c & 63;
    int ii = (i*NHEADS + h)*NQR + q;
    int jj = (j*NHEADS + h)*NQR + q;
    float mi = m1[ii], mj = m2[jj];
    float mm = fmaxf(mi, mj);
    float a1 = __expf(mi - mm), a2 = __expf(mj - mm);
    float rden = 1.f / (a1*z1[ii] + a2*z2[jj]);
    vrow[c] = (a1*u1[(size_t)ii*64 + d] - a2*u2[(size_t)jj*64 + d]) * rden;
  }
}

// ---------------------------------------------------------------------------
extern "C" void kernel_launch(void* const* d_in, const int* in_sizes, int n_in,
                              void* d_out, int out_size, void* d_ws, size_t ws_size,
                              hipStream_t stream)
{
  const float* q_x    = (const float*)d_in[0];
  const float* kv_x   = (const float*)d_in[1];
  const float* ppe    = (const float*)d_in[2];
  const float* q_w    = (const float*)d_in[3];
  const float* q_b    = (const float*)d_in[4];
  const float* kv_w   = (const float*)d_in[5];
  const float* kv_b   = (const float*)d_in[6];
  const float* out_w  = (const float*)d_in[7];
  const float* out_b  = (const float*)d_in[8];
  const float* lnq_w  = (const float*)d_in[9];
  const float* lnq_b  = (const float*)d_in[10];
  const float* lnkv_w = (const float*)d_in[11];
  const float* lnkv_b = (const float*)d_in[12];
  float* out = (float*)d_out;

  // workspace layout (floats); values aliases kv_y (dead after ln_rows)
  float* ws    = (float*)d_ws;
  float* q_ln  = ws;                         // 8*768            = 6144
  float* kv_y  = q_ln + NQR*D_MODEL;         // 3152*768         = 2420736
  float* kv_ln = kv_y + (size_t)MKV*D_MODEL; // 3152*768         = 2420736
  float* m1    = kv_ln + (size_t)MKV*D_MODEL;// 16*12*8          = 1536
  float* z1    = m1 + BB*NHEADS*NQR;
  float* m2    = z1 + BB*NHEADS*NQR;
  float* z2    = m2 + BB*NHEADS*NQR;
  float* u1    = z2 + BB*NHEADS*NQR;         // 16*12*8*64       = 98304
  float* u2    = u1 + BB*NHEADS*NQR*DHEAD;
  float* values = kv_y;                      // reuse (1572864 <= 2420736)

  qpath_kernel<<<NQR, 256, 0, stream>>>(q_x, q_w, q_b, lnq_w, lnq_b, q_ln);

  gemm_nt_kernel<<<dim3((MKV+63)/64, D_MODEL/64), 256, 0, stream>>>(
      kv_x, kv_w, nullptr, kv_y, MKV, D_MODEL, D_MODEL);

  ln_rows_kernel<<<MKV, 256, 0, stream>>>(kv_y, kv_b, lnkv_w, lnkv_b, kv_ln);

  rank_partials_kernel<<<dim3(BB, NHEADS, 2), 256, 0, stream>>>(
      kv_ln, q_ln, ppe, m1, z1, u1, m2, z2, u2);

  combine_kernel<<<dim3(NPAIR, NQR), 256, 0, stream>>>(
      m1, z1, u1, m2, z2, u2, values);

  gemm_nt_kernel<<<dim3(MOUT/64, D_MODEL/64), 256, 0, stream>>>(
      values, out_w, out_b, out, MOUT, D_MODEL, D_MODEL);
}

// Round 2
// 216.010 us; speedup vs baseline: 1.4861x; 1.4861x over previous
//
#include <hip/hip_runtime.h>
#include <hip/hip_bf16.h>
#include <math.h>

#define D_MODEL 768
#define NHEADS  12
#define DHEAD   64
#define NQR     8     // query rows
#define BB      16    // batch (ranks)
#define PP      197   // tokens per rank
#define NPAIR   256   // BB*BB
#define MKV     (BB*PP)     // 3152
#define MOUT    (NPAIR*NQR) // 2048
#define LN_EPSF 1e-5f
#define SCALEF  0.125f      // 64^-0.5

// ---------------------------------------------------------------------------
// q GEMM: qy[8,768] = qx[8,768] @ qw[768,768]^T   (no bias; LN adds it after)
// 96 blocks x 256 threads; 8 cols/block x 32 lanes/col, coalesced float4 w-reads.
// ---------------------------------------------------------------------------
__global__ __launch_bounds__(256) void qgemm_kernel(
    const float* __restrict__ qx, const float* __restrict__ qw,
    float* __restrict__ qy)
{
  __shared__ float xs[NQR*D_MODEL];   // 24 KB
  int tid = threadIdx.x;
  for (int e = tid*4; e < NQR*D_MODEL; e += 1024)
    *(float4*)&xs[e] = *(const float4*)&qx[e];
  __syncthreads();
  int col = tid >> 5, lane = tid & 31;
  int c = blockIdx.x*8 + col;
  const float* wr = qw + (size_t)c*D_MODEL;
  float acc[NQR] = {};
  for (int k = lane*4; k < D_MODEL; k += 128){
    float4 w4 = *(const float4*)&wr[k];
    #pragma unroll
    for (int q = 0; q < NQR; q++){
      float4 x4 = *(const float4*)&xs[q*D_MODEL + k];
      acc[q] += x4.x*w4.x + x4.y*w4.y + x4.z*w4.z + x4.w*w4.w;
    }
  }
  #pragma unroll
  for (int q = 0; q < NQR; q++){
    float a = acc[q];
    for (int off = 16; off >= 1; off >>= 1) a += __shfl_xor(a, off, 32);
    if (lane == 0) qy[q*D_MODEL + c] = a;
  }
}

// ---------------------------------------------------------------------------
// Tiled f32 GEMM: C[M,N] = A[M,K] @ W[N,K]^T.  64x64 tile, BK=16,
// 256 threads, 4x4 micro-tile.  (kv projection only now)
// ---------------------------------------------------------------------------
__global__ __launch_bounds__(256) void gemm_nt_kernel(
    const float* __restrict__ A, const float* __restrict__ W,
    float* __restrict__ C, int M, int N, int K)
{
  __shared__ __align__(16) float As[16][68];
  __shared__ __align__(16) float Bs[16][68];
  int tid = threadIdx.x;
  int m0 = blockIdx.x*64, n0 = blockIdx.y*64;
  int tx = tid & 15, ty = tid >> 4;
  int lrow = tid >> 2, lk = (tid & 3) << 2;
  float acc[4][4] = {};
  const float* aptr = A + (size_t)(m0 + lrow)*K + lk;
  const float* bptr = W + (size_t)(n0 + lrow)*K + lk;
  bool avalid = (m0 + lrow) < M;
  for (int kt = 0; kt < K; kt += 16){
    float4 av = avalid ? *(const float4*)(aptr + kt) : make_float4(0.f,0.f,0.f,0.f);
    float4 bv = *(const float4*)(bptr + kt);
    __syncthreads();
    As[lk+0][lrow] = av.x; As[lk+1][lrow] = av.y;
    As[lk+2][lrow] = av.z; As[lk+3][lrow] = av.w;
    Bs[lk+0][lrow] = bv.x; Bs[lk+1][lrow] = bv.y;
    Bs[lk+2][lrow] = bv.z; Bs[lk+3][lrow] = bv.w;
    __syncthreads();
    #pragma unroll
    for (int k = 0; k < 16; k++){
      float4 a4 = *(const float4*)&As[k][ty<<2];
      float4 b4 = *(const float4*)&Bs[k][tx<<2];
      float ar[4] = {a4.x, a4.y, a4.z, a4.w};
      float br[4] = {b4.x, b4.y, b4.z, b4.w};
      #pragma unroll
      for (int r = 0; r < 4; r++)
        #pragma unroll
        for (int c = 0; c < 4; c++)
          acc[r][c] += ar[r]*br[c];
    }
  }
  for (int r = 0; r < 4; r++){
    int m = m0 + (ty<<2) + r;
    if (m < M){
      float4 o = make_float4(acc[r][0], acc[r][1], acc[r][2], acc[r][3]);
      *(float4*)&C[(size_t)m*N + n0 + (tx<<2)] = o;
    }
  }
}

// ---------------------------------------------------------------------------
// Per-row LN with bias: out[r,:] = LN(Y[r,:] + bias) * lnw + lnb
// ---------------------------------------------------------------------------
__global__ __launch_bounds__(256) void ln_rows_kernel(
    const float* __restrict__ Y, const float* __restrict__ bias,
    const float* __restrict__ lnw, const float* __restrict__ lnb,
    float* __restrict__ out)
{
  __shared__ float red[256], red2[256];
  int r = blockIdx.x, tid = threadIdx.x;
  const float* yr = Y + (size_t)r*D_MODEL;
  float x0 = yr[tid      ] + bias[tid      ];
  float x1 = yr[tid + 256] + bias[tid + 256];
  float x2 = yr[tid + 512] + bias[tid + 512];
  red[tid] = x0 + x1 + x2; red2[tid] = x0*x0 + x1*x1 + x2*x2;
  __syncthreads();
  for (int st = 128; st > 0; st >>= 1){
    if (tid < st){ red[tid] += red[tid+st]; red2[tid] += red2[tid+st]; }
    __syncthreads();
  }
  float mean = red[0]*(1.f/768.f);
  float var  = red2[0]*(1.f/768.f) - mean*mean;
  float inv  = rsqrtf(var + LN_EPSF);
  float* orow = out + (size_t)r*D_MODEL;
  orow[tid      ] = (x0-mean)*inv*lnw[tid      ] + lnb[tid      ];
  orow[tid + 256] = (x1-mean)*inv*lnw[tid + 256] + lnb[tid + 256];
  orow[tid + 512] = (x2-mean)*inv*lnw[tid + 512] + lnb[tid + 512];
}

// ---------------------------------------------------------------------------
// Per-(rank, head, half) attention partials (unchanged from R1).
// ---------------------------------------------------------------------------
__global__ __launch_bounds__(256) void rank_partials_kernel(
    const float* __restrict__ kv_ln, const float* __restrict__ q_ln,
    const float* __restrict__ ppe,
    float* __restrict__ m1O, float* __restrict__ z1O, float* __restrict__ u1O,
    float* __restrict__ m2O, float* __restrict__ z2O, float* __restrict__ u2O)
{
  __shared__ float A[PP*65];
  __shared__ float qs[NQR*64];
  __shared__ float E[NQR*PP];
  int r = blockIdx.x, h = blockIdx.y, half = blockIdx.z;
  int tid = threadIdx.x;

  for (int e = tid; e < NQR*64; e += 256){
    int q = e >> 6, d = e & 63;
    qs[e] = q_ln[q*D_MODEL + h*64 + d];
  }
  for (int e = tid; e < PP*64; e += 256){
    int p = e >> 6, d = e & 63;
    A[p*65 + d] = kv_ln[((size_t)(r*PP + p))*D_MODEL + h*64 + d]
                + ppe[((size_t)(half*PP + p))*D_MODEL + h*64 + d];
  }
  __syncthreads();

  int q = tid >> 5, sub = tid & 31;
  float s[7];
  #pragma unroll
  for (int i = 0; i < 7; i++) s[i] = 0.f;
  for (int d = 0; d < 64; d++){
    float qv = qs[q*64 + d];
    #pragma unroll
    for (int i = 0; i < 7; i++){
      int p = sub + 32*i;
      int pc = p < PP ? p : PP-1;
      s[i] += qv * A[pc*65 + d];
    }
  }
  float mloc = -1e30f;
  #pragma unroll
  for (int i = 0; i < 7; i++){
    int p = sub + 32*i;
    s[i] = (p < PP) ? s[i]*SCALEF : -1e30f;
    mloc = fmaxf(mloc, s[i]);
  }
  for (int off = 16; off >= 1; off >>= 1)
    mloc = fmaxf(mloc, __shfl_xor(mloc, off, 32));
  float zloc = 0.f;
  #pragma unroll
  for (int i = 0; i < 7; i++){
    int p = sub + 32*i;
    float e = __expf(s[i] - mloc);
    if (p < PP){ E[q*PP + p] = e; zloc += e; }
  }
  for (int off = 16; off >= 1; off >>= 1)
    zloc += __shfl_xor(zloc, off, 32);

  int idx = (r*NHEADS + h)*NQR + q;
  float* mO = half ? m2O : m1O;
  float* zO = half ? z2O : z1O;
  float* uO = half ? u2O : u1O;
  if (sub == 0){ mO[idx] = mloc; zO[idx] = zloc; }
  __syncthreads();

  float u0 = 0.f, u1 = 0.f;
  for (int p = 0; p < PP; p++){
    float e = E[q*PP + p];
    u0 += e * A[p*65 + sub];
    u1 += e * A[p*65 + sub + 32];
  }
  uO[(size_t)idx*64 + sub]      = u0;
  uO[(size_t)idx*64 + sub + 32] = u1;
}

// ---------------------------------------------------------------------------
// Rank-partial projection through out_w, per head:
//   P[i,h,q,n] = sum_d U[i,h,q,d] * out_w[n, h*64+d]
// grid (h=12, n-tile=6, which=2); block 256 = 16x16, 8x8 micro, K=64.
// ---------------------------------------------------------------------------
__global__ __launch_bounds__(256) void proj_kernel(
    const float* __restrict__ u1, const float* __restrict__ u2,
    const float* __restrict__ ow, float* __restrict__ p1, float* __restrict__ p2)
{
  __shared__ float Us[128][65];
  __shared__ float Ws[128][65];
  int h = blockIdx.x, n0 = blockIdx.y*128;
  const float* U = blockIdx.z ? u2 : u1;
  float*       P = blockIdx.z ? p2 : p1;
  int tid = threadIdx.x;
  for (int e = tid; e < 128*16; e += 256){
    int m = e >> 4, d4 = (e & 15) << 2;
    int i = m >> 3, q = m & 7;
    float4 v = *(const float4*)&U[(((size_t)i*NHEADS + h)*NQR + q)*64 + d4];
    Us[m][d4] = v.x; Us[m][d4+1] = v.y; Us[m][d4+2] = v.z; Us[m][d4+3] = v.w;
  }
  for (int e = tid; e < 128*16; e += 256){
    int n = e >> 4, d4 = (e & 15) << 2;
    float4 v = *(const float4*)&ow[((size_t)(n0+n))*D_MODEL + h*64 + d4];
    Ws[n][d4] = v.x; Ws[n][d4+1] = v.y; Ws[n][d4+2] = v.z; Ws[n][d4+3] = v.w;
  }
  __syncthreads();
  int tx = tid & 15, ty = tid >> 4;
  float acc[8][8] = {};
  for (int k = 0; k < 64; k++){
    float ur[8], wr[8];
    #pragma unroll
    for (int r = 0; r < 8; r++) ur[r] = Us[ty*8 + r][k];
    #pragma unroll
    for (int c = 0; c < 8; c++) wr[c] = Ws[tx*8 + c][k];
    #pragma unroll
    for (int r = 0; r < 8; r++)
      #pragma unroll
      for (int c = 0; c < 8; c++)
        acc[r][c] += ur[r]*wr[c];
  }
  #pragma unroll
  for (int r = 0; r < 8; r++){
    int m = ty*8 + r, i = m >> 3, q = m & 7;
    float* prow = P + (((size_t)i*NHEADS + h)*NQR + q)*D_MODEL + n0 + tx*8;
    *(float4*)&prow[0] = make_float4(acc[r][0], acc[r][1], acc[r][2], acc[r][3]);
    *(float4*)&prow[4] = make_float4(acc[r][4], acc[r][5], acc[r][6], acc[r][7]);
  }
}

// ---------------------------------------------------------------------------
// Final combine, writes output directly:
//   out[(i*16+j)*8+q, n] = sum_h c1[h]*P1[i,h,q,n] - c2[h]*P2[j,h,q,n] + out_b[n]
// ---------------------------------------------------------------------------
__global__ __launch_bounds__(256) void combine_out_kernel(
    const float* __restrict__ m1, const float* __restrict__ z1,
    const float* __restrict__ m2, const float* __restrict__ z2,
    const float* __restrict__ p1, const float* __restrict__ p2,
    const float* __restrict__ out_b, float* __restrict__ out)
{
  __shared__ float c1s[NHEADS], c2s[NHEADS];
  int pair = blockIdx.x, q = blockIdx.y, tid = threadIdx.x;
  int i = pair >> 4, j = pair & 15;
  if (tid < NHEADS){
    int h = tid;
    int ii = (i*NHEADS + h)*NQR + q;
    int jj = (j*NHEADS + h)*NQR + q;
    float mi = m1[ii], mj = m2[jj];
    float mm = fmaxf(mi, mj);
    float a1 = __expf(mi - mm), a2 = __expf(mj - mm);
    float rden = 1.f / (a1*z1[ii] + a2*z2[jj]);
    c1s[h] = a1*rden; c2s[h] = a2*rden;
  }
  __syncthreads();
  float* orow = out + ((size_t)(pair*NQR + q))*D_MODEL;
  for (int nn = tid; nn < D_MODEL; nn += 256){
    float acc = out_b[nn];
    #pragma unroll
    for (int h = 0; h < NHEADS; h++){
      acc += c1s[h]*p1[(((size_t)i*NHEADS + h)*NQR + q)*D_MODEL + nn]
           - c2s[h]*p2[(((size_t)j*NHEADS + h)*NQR + q)*D_MODEL + nn];
    }
    orow[nn] = acc;
  }
}

// ---------------------------------------------------------------------------
extern "C" void kernel_launch(void* const* d_in, const int* in_sizes, int n_in,
                              void* d_out, int out_size, void* d_ws, size_t ws_size,
                              hipStream_t stream)
{
  const float* q_x    = (const float*)d_in[0];
  const float* kv_x   = (const float*)d_in[1];
  const float* ppe    = (const float*)d_in[2];
  const float* q_w    = (const float*)d_in[3];
  const float* q_b    = (const float*)d_in[4];
  const float* kv_w   = (const float*)d_in[5];
  const float* kv_b   = (const float*)d_in[6];
  const float* out_w  = (const float*)d_in[7];
  const float* out_b  = (const float*)d_in[8];
  const float* lnq_w  = (const float*)d_in[9];
  const float* lnq_b  = (const float*)d_in[10];
  const float* lnkv_w = (const float*)d_in[11];
  const float* lnkv_b = (const float*)d_in[12];
  float* out = (float*)d_out;

  float* ws    = (float*)d_ws;
  float* q_y   = ws;                            // 8*768
  float* q_ln  = q_y  + NQR*D_MODEL;            // 8*768
  float* kv_y  = q_ln + NQR*D_MODEL;            // 3152*768
  float* kv_ln = kv_y + (size_t)MKV*D_MODEL;    // 3152*768
  float* m1    = kv_ln + (size_t)MKV*D_MODEL;   // 1536 each
  float* z1    = m1 + BB*NHEADS*NQR;
  float* m2    = z1 + BB*NHEADS*NQR;
  float* z2    = m2 + BB*NHEADS*NQR;
  float* u1    = z2 + BB*NHEADS*NQR;            // 98304 each
  float* u2    = u1 + BB*NHEADS*NQR*DHEAD;
  float* p1    = kv_y;                          // reuse: 16*12*8*768 = 1179648
  float* p2    = p1 + (size_t)BB*NHEADS*NQR*D_MODEL;  // total 2359296 <= 2420736

  qgemm_kernel<<<96, 256, 0, stream>>>(q_x, q_w, q_y);
  ln_rows_kernel<<<NQR, 256, 0, stream>>>(q_y, q_b, lnq_w, lnq_b, q_ln);

  gemm_nt_kernel<<<dim3((MKV+63)/64, D_MODEL/64), 256, 0, stream>>>(
      kv_x, kv_w, kv_y, MKV, D_MODEL, D_MODEL);
  ln_rows_kernel<<<MKV, 256, 0, stream>>>(kv_y, kv_b, lnkv_w, lnkv_b, kv_ln);

  rank_partials_kernel<<<dim3(BB, NHEADS, 2), 256, 0, stream>>>(
      kv_ln, q_ln, ppe, m1, z1, u1, m2, z2, u2);

  proj_kernel<<<dim3(NHEADS, D_MODEL/128, 2), 256, 0, stream>>>(
      u1, u2, out_w, p1, p2);

  combine_out_kernel<<<dim3(NPAIR, NQR), 256, 0, stream>>>(
      m1, z1, m2, z2, p1, p2, out_b, out);
}

// Round 3
// 188.884 us; speedup vs baseline: 1.6995x; 1.1436x over previous
//
#include <hip/hip_runtime.h>
#include <hip/hip_bf16.h>
#include <math.h>

#define D_MODEL 768
#define NHEADS  12
#define DHEAD   64
#define NQR     8     // query rows
#define BB      16    // batch (ranks)
#define PP      197   // tokens per rank
#define NPAIR   256   // BB*BB
#define MKV     (BB*PP)     // 3152
#define LN_EPSF 1e-5f
#define SCALEF  0.125f      // 64^-0.5

// split-bf16 K-extended GEMM params
#define KTOT  2304          // 3*768:  [a_hi|a_hi|a_lo] x [w_hi|w_lo|w_hi]
#define KSPLIT 2
#define KPER  (KTOT/KSPLIT) // 1152
#define MPAD  3200          // 25*128
#define BM 128
#define BN 128
#define BK 64

typedef __attribute__((ext_vector_type(8))) short short8v;   // 8 bf16
typedef __attribute__((ext_vector_type(4))) float float4v;   // mfma acc

__device__ __forceinline__ void gload16(const void* g, void* l){
  __builtin_amdgcn_global_load_lds(
      (const __attribute__((address_space(1))) unsigned int*)g,
      (__attribute__((address_space(3))) unsigned int*)l, 16, 0, 0);
}

// ---------------------------------------------------------------------------
// q GEMM: qy[8,768] = qx[8,768] @ qw[768,768]^T
// ---------------------------------------------------------------------------
__global__ __launch_bounds__(256) void qgemm_kernel(
    const float* __restrict__ qx, const float* __restrict__ qw,
    float* __restrict__ qy)
{
  __shared__ float xs[NQR*D_MODEL];
  int tid = threadIdx.x;
  for (int e = tid*4; e < NQR*D_MODEL; e += 1024)
    *(float4*)&xs[e] = *(const float4*)&qx[e];
  __syncthreads();
  int col = tid >> 5, lane = tid & 31;
  int c = blockIdx.x*8 + col;
  const float* wr = qw + (size_t)c*D_MODEL;
  float acc[NQR] = {};
  for (int k = lane*4; k < D_MODEL; k += 128){
    float4 w4 = *(const float4*)&wr[k];
    #pragma unroll
    for (int q = 0; q < NQR; q++){
      float4 x4 = *(const float4*)&xs[q*D_MODEL + k];
      acc[q] += x4.x*w4.x + x4.y*w4.y + x4.z*w4.z + x4.w*w4.w;
    }
  }
  #pragma unroll
  for (int q = 0; q < NQR; q++){
    float a = acc[q];
    for (int off = 16; off >= 1; off >>= 1) a += __shfl_xor(a, off, 32);
    if (lane == 0) qy[q*D_MODEL + c] = a;
  }
}

// ---------------------------------------------------------------------------
// pack: f32 row [768] -> bf16 row [2304] as three 768-segments.
// mode 0 (activations): [hi, hi, lo]    mode 1 (weights): [hi, lo, hi]
// rows beyond rows_valid are zero-filled (M padding for the GEMM).
// ---------------------------------------------------------------------------
__global__ __launch_bounds__(192) void pack_kernel(
    const float* __restrict__ X, __hip_bfloat16* __restrict__ Y,
    int rows_valid, int mode)
{
  int m = blockIdx.x, t = threadIdx.x;
  int k = t*4;
  float4 v = (m < rows_valid) ? *(const float4*)&X[(size_t)m*D_MODEL + k]
                              : make_float4(0.f,0.f,0.f,0.f);
  float xsv[4] = {v.x, v.y, v.z, v.w};
  unsigned short hu[4], lu[4];
  #pragma unroll
  for (int i = 0; i < 4; i++){
    __hip_bfloat16 h = __float2bfloat16(xsv[i]);
    float hf = __bfloat162float(h);
    __hip_bfloat16 l = __float2bfloat16(xsv[i] - hf);
    hu[i] = *(unsigned short*)&h;
    lu[i] = *(unsigned short*)&l;
  }
  ushort4 hv = {hu[0], hu[1], hu[2], hu[3]};
  ushort4 lv = {lu[0], lu[1], lu[2], lu[3]};
  ushort4* row = (ushort4*)(Y + (size_t)m*KTOT);
  int s = k >> 2;                 // 0..191 (ushort4 units per 768-segment)
  if (mode == 0){ row[s] = hv; row[s+192] = hv; row[s+384] = lv; }
  else          { row[s] = hv; row[s+192] = lv; row[s+384] = hv; }
}

// ---------------------------------------------------------------------------
// bf16 MFMA GEMM (m97 structure): C[kt][m][n] partial over K-split.
// A' [MPAD][KTOT] bf16, W' [768][KTOT] bf16, both row-major k-contiguous.
// 128x128 tile, BK=64, 256 thr = 4 waves (2x2 of 64x64), 16x16x32 MFMA.
// LDS slots xor-swizzled (kg ^= row&7) -> conflict-free ds_read_b128;
// swizzle applied via per-lane GLOBAL source addr (global_load_lds's LDS
// dst must stay lane-contiguous).
// ---------------------------------------------------------------------------
__global__ __launch_bounds__(256) void gemm_mfma_kernel(
    const __hip_bfloat16* __restrict__ Ab, const __hip_bfloat16* __restrict__ Wb,
    float* __restrict__ Cp)
{
  __shared__ __hip_bfloat16 As[BM*BK];   // 16 KB
  __shared__ __hip_bfloat16 Bs[BN*BK];   // 16 KB
  int tid = threadIdx.x;
  int wave = tid >> 6, lane = tid & 63;
  int m0 = blockIdx.x*BM, n0 = blockIdx.y*BN, kt = blockIdx.z;
  int wr = wave >> 1, wc = wave & 1;

  float4v acc[4][4];
  #pragma unroll
  for (int i = 0; i < 4; i++)
    #pragma unroll
    for (int j = 0; j < 4; j++)
      acc[i][j] = (float4v){0.f, 0.f, 0.f, 0.f};

  // staging slot for this lane: 4 instrs/wave for A, 4 for B
  int sbase = wave*256;
  for (int st = 0; st < KPER/BK; ++st){
    int k0 = kt*KPER + st*BK;
    __syncthreads();
    #pragma unroll
    for (int i = 0; i < 4; i++){
      int s  = sbase + i*64 + lane;
      int r  = s >> 3, kg = s & 7;
      int kgg = kg ^ (r & 7);
      gload16(Ab + (size_t)(m0 + r)*KTOT + k0 + kgg*8, (char*)As + (size_t)s*16);
      gload16(Wb + (size_t)(n0 + r)*KTOT + k0 + kgg*8, (char*)Bs + (size_t)s*16);
    }
    __syncthreads();
    #pragma unroll
    for (int ks = 0; ks < 2; ks++){
      int kq = ks*4 + (lane >> 4);   // kgroup 0..7 within stage
      short8v af[4], bf[4];
      #pragma unroll
      for (int t = 0; t < 4; t++){
        int ar = wr*64 + t*16 + (lane & 15);
        int as_ = ar*8 + (kq ^ (ar & 7));
        af[t] = *(const short8v*)((const char*)As + (size_t)as_*16);
        int br = wc*64 + t*16 + (lane & 15);
        int bs_ = br*8 + (kq ^ (br & 7));
        bf[t] = *(const short8v*)((const char*)Bs + (size_t)bs_*16);
      }
      #pragma unroll
      for (int i = 0; i < 4; i++)
        #pragma unroll
        for (int j = 0; j < 4; j++)
          acc[i][j] = __builtin_amdgcn_mfma_f32_16x16x32_bf16(af[i], bf[j], acc[i][j], 0, 0, 0);
    }
  }

  float* C = Cp + (size_t)kt*MKV*D_MODEL;
  #pragma unroll
  for (int i = 0; i < 4; i++){
    int mb = m0 + wr*64 + i*16 + ((lane >> 4) << 2);
    #pragma unroll
    for (int j = 0; j < 4; j++){
      int n = n0 + wc*64 + j*16 + (lane & 15);
      #pragma unroll
      for (int r = 0; r < 4; r++){
        int m = mb + r;
        if (m < MKV) C[(size_t)m*D_MODEL + n] = acc[i][j][r];
      }
    }
  }
}

// ---------------------------------------------------------------------------
// LN over y0[r]+bias (single input, q path)
// ---------------------------------------------------------------------------
__global__ __launch_bounds__(256) void ln_rows_kernel(
    const float* __restrict__ Y, const float* __restrict__ bias,
    const float* __restrict__ lnw, const float* __restrict__ lnb,
    float* __restrict__ out)
{
  __shared__ float red[256], red2[256];
  int r = blockIdx.x, tid = threadIdx.x;
  const float* yr = Y + (size_t)r*D_MODEL;
  float x0 = yr[tid      ] + bias[tid      ];
  float x1 = yr[tid + 256] + bias[tid + 256];
  float x2 = yr[tid + 512] + bias[tid + 512];
  red[tid] = x0 + x1 + x2; red2[tid] = x0*x0 + x1*x1 + x2*x2;
  __syncthreads();
  for (int st = 128; st > 0; st >>= 1){
    if (tid < st){ red[tid] += red[tid+st]; red2[tid] += red2[tid+st]; }
    __syncthreads();
  }
  float mean = red[0]*(1.f/768.f);
  float var  = red2[0]*(1.f/768.f) - mean*mean;
  float inv  = rsqrtf(var + LN_EPSF);
  float* orow = out + (size_t)r*D_MODEL;
  orow[tid      ] = (x0-mean)*inv*lnw[tid      ] + lnb[tid      ];
  orow[tid + 256] = (x1-mean)*inv*lnw[tid + 256] + lnb[tid + 256];
  orow[tid + 512] = (x2-mean)*inv*lnw[tid + 512] + lnb[tid + 512];
}

// ---------------------------------------------------------------------------
// LN over y0[r]+y1[r]+bias (dual input: sums the split-K GEMM partials)
// ---------------------------------------------------------------------------
__global__ __launch_bounds__(256) void ln_rows2_kernel(
    const float* __restrict__ Y0, const float* __restrict__ Y1,
    const float* __restrict__ bias,
    const float* __restrict__ lnw, const float* __restrict__ lnb,
    float* __restrict__ out)
{
  __shared__ float red[256], red2[256];
  int r = blockIdx.x, tid = threadIdx.x;
  const float* y0 = Y0 + (size_t)r*D_MODEL;
  const float* y1 = Y1 + (size_t)r*D_MODEL;
  float x0 = y0[tid      ] + y1[tid      ] + bias[tid      ];
  float x1 = y0[tid + 256] + y1[tid + 256] + bias[tid + 256];
  float x2 = y0[tid + 512] + y1[tid + 512] + bias[tid + 512];
  red[tid] = x0 + x1 + x2; red2[tid] = x0*x0 + x1*x1 + x2*x2;
  __syncthreads();
  for (int st = 128; st > 0; st >>= 1){
    if (tid < st){ red[tid] += red[tid+st]; red2[tid] += red2[tid+st]; }
    __syncthreads();
  }
  float mean = red[0]*(1.f/768.f);
  float var  = red2[0]*(1.f/768.f) - mean*mean;
  float inv  = rsqrtf(var + LN_EPSF);
  float* orow = out + (size_t)r*D_MODEL;
  orow[tid      ] = (x0-mean)*inv*lnw[tid      ] + lnb[tid      ];
  orow[tid + 256] = (x1-mean)*inv*lnw[tid + 256] + lnb[tid + 256];
  orow[tid + 512] = (x2-mean)*inv*lnw[tid + 512] + lnb[tid + 512];
}

// ---------------------------------------------------------------------------
// Per-(rank, head, half) attention partials.
// ---------------------------------------------------------------------------
__global__ __launch_bounds__(256) void rank_partials_kernel(
    const float* __restrict__ kv_ln, const float* __restrict__ q_ln,
    const float* __restrict__ ppe,
    float* __restrict__ m1O, float* __restrict__ z1O, float* __restrict__ u1O,
    float* __restrict__ m2O, float* __restrict__ z2O, float* __restrict__ u2O)
{
  __shared__ float A[PP*65];
  __shared__ float qs[NQR*64];
  __shared__ float E[NQR*PP];
  int r = blockIdx.x, h = blockIdx.y, half = blockIdx.z;
  int tid = threadIdx.x;

  for (int e = tid; e < NQR*64; e += 256){
    int q = e >> 6, d = e & 63;
    qs[e] = q_ln[q*D_MODEL + h*64 + d];
  }
  for (int e = tid; e < PP*64; e += 256){
    int p = e >> 6, d = e & 63;
    A[p*65 + d] = kv_ln[((size_t)(r*PP + p))*D_MODEL + h*64 + d]
                + ppe[((size_t)(half*PP + p))*D_MODEL + h*64 + d];
  }
  __syncthreads();

  int q = tid >> 5, sub = tid & 31;
  float s[7];
  #pragma unroll
  for (int i = 0; i < 7; i++) s[i] = 0.f;
  for (int d = 0; d < 64; d++){
    float qv = qs[q*64 + d];
    #pragma unroll
    for (int i = 0; i < 7; i++){
      int p = sub + 32*i;
      int pc = p < PP ? p : PP-1;
      s[i] += qv * A[pc*65 + d];
    }
  }
  float mloc = -1e30f;
  #pragma unroll
  for (int i = 0; i < 7; i++){
    int p = sub + 32*i;
    s[i] = (p < PP) ? s[i]*SCALEF : -1e30f;
    mloc = fmaxf(mloc, s[i]);
  }
  for (int off = 16; off >= 1; off >>= 1)
    mloc = fmaxf(mloc, __shfl_xor(mloc, off, 32));
  float zloc = 0.f;
  #pragma unroll
  for (int i = 0; i < 7; i++){
    int p = sub + 32*i;
    float e = __expf(s[i] - mloc);
    if (p < PP){ E[q*PP + p] = e; zloc += e; }
  }
  for (int off = 16; off >= 1; off >>= 1)
    zloc += __shfl_xor(zloc, off, 32);

  int idx = (r*NHEADS + h)*NQR + q;
  float* mO = half ? m2O : m1O;
  float* zO = half ? z2O : z1O;
  float* uO = half ? u2O : u1O;
  if (sub == 0){ mO[idx] = mloc; zO[idx] = zloc; }
  __syncthreads();

  float u0 = 0.f, u1 = 0.f;
  for (int p = 0; p < PP; p++){
    float e = E[q*PP + p];
    u0 += e * A[p*65 + sub];
    u1 += e * A[p*65 + sub + 32];
  }
  uO[(size_t)idx*64 + sub]      = u0;
  uO[(size_t)idx*64 + sub + 32] = u1;
}

// ---------------------------------------------------------------------------
// Rank-partial projection through out_w, per head:
//   P[i,h,q,n] = sum_d U[i,h,q,d] * out_w[n, h*64+d]
// ---------------------------------------------------------------------------
__global__ __launch_bounds__(256) void proj_kernel(
    const float* __restrict__ u1, const float* __restrict__ u2,
    const float* __restrict__ ow, float* __restrict__ p1, float* __restrict__ p2)
{
  __shared__ float Us[128][65];
  __shared__ float Ws[128][65];
  int h = blockIdx.x, n0 = blockIdx.y*128;
  const float* U = blockIdx.z ? u2 : u1;
  float*       P = blockIdx.z ? p2 : p1;
  int tid = threadIdx.x;
  for (int e = tid; e < 128*16; e += 256){
    int m = e >> 4, d4 = (e & 15) << 2;
    int i = m >> 3, q = m & 7;
    float4 v = *(const float4*)&U[(((size_t)i*NHEADS + h)*NQR + q)*64 + d4];
    Us[m][d4] = v.x; Us[m][d4+1] = v.y; Us[m][d4+2] = v.z; Us[m][d4+3] = v.w;
  }
  for (int e = tid; e < 128*16; e += 256){
    int n = e >> 4, d4 = (e & 15) << 2;
    float4 v = *(const float4*)&ow[((size_t)(n0+n))*D_MODEL + h*64 + d4];
    Ws[n][d4] = v.x; Ws[n][d4+1] = v.y; Ws[n][d4+2] = v.z; Ws[n][d4+3] = v.w;
  }
  __syncthreads();
  int tx = tid & 15, ty = tid >> 4;
  float acc[8][8] = {};
  for (int k = 0; k < 64; k++){
    float ur[8], wr[8];
    #pragma unroll
    for (int r = 0; r < 8; r++) ur[r] = Us[ty*8 + r][k];
    #pragma unroll
    for (int c = 0; c < 8; c++) wr[c] = Ws[tx*8 + c][k];
    #pragma unroll
    for (int r = 0; r < 8; r++)
      #pragma unroll
      for (int c = 0; c < 8; c++)
        acc[r][c] += ur[r]*wr[c];
  }
  #pragma unroll
  for (int r = 0; r < 8; r++){
    int m = ty*8 + r, i = m >> 3, q = m & 7;
    float* prow = P + (((size_t)i*NHEADS + h)*NQR + q)*D_MODEL + n0 + tx*8;
    *(float4*)&prow[0] = make_float4(acc[r][0], acc[r][1], acc[r][2], acc[r][3]);
    *(float4*)&prow[4] = make_float4(acc[r][4], acc[r][5], acc[r][6], acc[r][7]);
  }
}

// ---------------------------------------------------------------------------
// Final combine:
//   out[(i*16+j)*8+q, n] = sum_h c1[h]*P1[i,h,q,n] - c2[h]*P2[j,h,q,n] + out_b[n]
// ---------------------------------------------------------------------------
__global__ __launch_bounds__(256) void combine_out_kernel(
    const float* __restrict__ m1, const float* __restrict__ z1,
    const float* __restrict__ m2, const float* __restrict__ z2,
    const float* __restrict__ p1, const float* __restrict__ p2,
    const float* __restrict__ out_b, float* __restrict__ out)
{
  __shared__ float c1s[NHEADS], c2s[NHEADS];
  int pair = blockIdx.x, q = blockIdx.y, tid = threadIdx.x;
  int i = pair >> 4, j = pair & 15;
  if (tid < NHEADS){
    int h = tid;
    int ii = (i*NHEADS + h)*NQR + q;
    int jj = (j*NHEADS + h)*NQR + q;
    float mi = m1[ii], mj = m2[jj];
    float mm = fmaxf(mi, mj);
    float a1 = __expf(mi - mm), a2 = __expf(mj - mm);
    float rden = 1.f / (a1*z1[ii] + a2*z2[jj]);
    c1s[h] = a1*rden; c2s[h] = a2*rden;
  }
  __syncthreads();
  float* orow = out + ((size_t)(pair*NQR + q))*D_MODEL;
  for (int nn = tid; nn < D_MODEL; nn += 256){
    float acc = out_b[nn];
    #pragma unroll
    for (int h = 0; h < NHEADS; h++){
      acc += c1s[h]*p1[(((size_t)i*NHEADS + h)*NQR + q)*D_MODEL + nn]
           - c2s[h]*p2[(((size_t)j*NHEADS + h)*NQR + q)*D_MODEL + nn];
    }
    orow[nn] = acc;
  }
}

// ---------------------------------------------------------------------------
extern "C" void kernel_launch(void* const* d_in, const int* in_sizes, int n_in,
                              void* d_out, int out_size, void* d_ws, size_t ws_size,
                              hipStream_t stream)
{
  const float* q_x    = (const float*)d_in[0];
  const float* kv_x   = (const float*)d_in[1];
  const float* ppe    = (const float*)d_in[2];
  const float* q_w    = (const float*)d_in[3];
  const float* q_b    = (const float*)d_in[4];
  const float* kv_w   = (const float*)d_in[5];
  const float* kv_b   = (const float*)d_in[6];
  const float* out_w  = (const float*)d_in[7];
  const float* out_b  = (const float*)d_in[8];
  const float* lnq_w  = (const float*)d_in[9];
  const float* lnq_b  = (const float*)d_in[10];
  const float* lnkv_w = (const float*)d_in[11];
  const float* lnkv_b = (const float*)d_in[12];
  float* out = (float*)d_out;

  // workspace (f32 units). Aliasing by lifetime:
  //   Abuf (bf16 A', dead after gemm)  <- later kv_ln
  //   Wbuf (bf16 W', dead after gemm)  <- later m/z/u partials
  //   C0,C1 (gemm partials, dead after ln2) <- later p1,p2
  float* ws    = (float*)d_ws;
  float* q_y   = ws;                              //  6144
  float* q_ln  = q_y  + NQR*D_MODEL;              //  6144
  float* Abuf_f = q_ln + NQR*D_MODEL;             //  3,686,400 (3200*2304 bf16)
  float* Wbuf_f = Abuf_f + (size_t)MPAD*KTOT/2;   //    884,736 (768*2304 bf16)
  float* Creg  = Wbuf_f + (size_t)D_MODEL*KTOT/2; //  2x 2,420,736
  float* C0    = Creg;
  float* C1    = C0 + (size_t)MKV*D_MODEL;

  __hip_bfloat16* Abuf = (__hip_bfloat16*)Abuf_f;
  __hip_bfloat16* Wbuf = (__hip_bfloat16*)Wbuf_f;

  float* kv_ln = Abuf_f;                          // alias (2,420,736 <= 3,686,400)
  float* m1    = Wbuf_f;                          // alias region (202,752 <= 884,736)
  float* z1    = m1 + BB*NHEADS*NQR;
  float* m2    = z1 + BB*NHEADS*NQR;
  float* z2    = m2 + BB*NHEADS*NQR;
  float* u1    = z2 + BB*NHEADS*NQR;
  float* u2    = u1 + BB*NHEADS*NQR*DHEAD;
  float* p1    = Creg;                            // alias (2,359,296 <= 4,841,472)
  float* p2    = p1 + (size_t)BB*NHEADS*NQR*D_MODEL;

  qgemm_kernel<<<96, 256, 0, stream>>>(q_x, q_w, q_y);
  ln_rows_kernel<<<NQR, 256, 0, stream>>>(q_y, q_b, lnq_w, lnq_b, q_ln);

  pack_kernel<<<MPAD, 192, 0, stream>>>(kv_x, Abuf, MKV, 0);
  pack_kernel<<<D_MODEL, 192, 0, stream>>>(kv_w, Wbuf, D_MODEL, 1);

  gemm_mfma_kernel<<<dim3(MPAD/BM, D_MODEL/BN, KSPLIT), 256, 0, stream>>>(
      Abuf, Wbuf, C0);

  ln_rows2_kernel<<<MKV, 256, 0, stream>>>(C0, C1, kv_b, lnkv_w, lnkv_b, kv_ln);

  rank_partials_kernel<<<dim3(BB, NHEADS, 2), 256, 0, stream>>>(
      kv_ln, q_ln, ppe, m1, z1, u1, m2, z2, u2);

  proj_kernel<<<dim3(NHEADS, D_MODEL/128, 2), 256, 0, stream>>>(
      u1, u2, out_w, p1, p2);

  combine_out_kernel<<<dim3(NPAIR, NQR), 256, 0, stream>>>(
      m1, z1, m2, z2, p1, p2, out_b, out);
}

// Round 4
// 182.381 us; speedup vs baseline: 1.7601x; 1.0357x over previous
//
#include <hip/hip_runtime.h>
#include <hip/hip_bf16.h>
#include <math.h>

#define D_MODEL 768
#define NHEADS  12
#define DHEAD   64
#define NQR     8     // query rows
#define BB      16    // batch (ranks)
#define PP      197   // tokens per rank
#define NPAIR   256   // BB*BB
#define MKV     (BB*PP)     // 3152
#define LN_EPSF 1e-5f
#define SCALEF  0.125f      // 64^-0.5

// split-bf16 K-extended GEMM params
#define KTOT  2304          // 3*768:  [a_hi|a_hi|a_lo] x [w_hi|w_lo|w_hi]
#define KSPLIT 3
#define KPER  (KTOT/KSPLIT) // 768
#define MPAD  3200          // 25*128
#define BM 128
#define BN 128
#define BK 64

typedef __attribute__((ext_vector_type(8))) short short8v;   // 8 bf16
typedef __attribute__((ext_vector_type(4))) float float4v;   // mfma acc

__device__ __forceinline__ void gload16(const void* g, void* l){
  __builtin_amdgcn_global_load_lds(
      (const __attribute__((address_space(1))) unsigned int*)g,
      (__attribute__((address_space(3))) unsigned int*)l, 16, 0, 0);
}

// ---------------------------------------------------------------------------
// q GEMM: qy[8,768] = qx[8,768] @ qw[768,768]^T
// ---------------------------------------------------------------------------
__global__ __launch_bounds__(256) void qgemm_kernel(
    const float* __restrict__ qx, const float* __restrict__ qw,
    float* __restrict__ qy)
{
  __shared__ float xs[NQR*D_MODEL];
  int tid = threadIdx.x;
  for (int e = tid*4; e < NQR*D_MODEL; e += 1024)
    *(float4*)&xs[e] = *(const float4*)&qx[e];
  __syncthreads();
  int col = tid >> 5, lane = tid & 31;
  int c = blockIdx.x*8 + col;
  const float* wr = qw + (size_t)c*D_MODEL;
  float acc[NQR] = {};
  for (int k = lane*4; k < D_MODEL; k += 128){
    float4 w4 = *(const float4*)&wr[k];
    #pragma unroll
    for (int q = 0; q < NQR; q++){
      float4 x4 = *(const float4*)&xs[q*D_MODEL + k];
      acc[q] += x4.x*w4.x + x4.y*w4.y + x4.z*w4.z + x4.w*w4.w;
    }
  }
  #pragma unroll
  for (int q = 0; q < NQR; q++){
    float a = acc[q];
    for (int off = 16; off >= 1; off >>= 1) a += __shfl_xor(a, off, 32);
    if (lane == 0) qy[q*D_MODEL + c] = a;
  }
}

// ---------------------------------------------------------------------------
// fused pack: f32 row [768] -> bf16 row [2304] as three 768-segments.
// blocks [0, MPAD)        : activations (kv_x), layout [hi, hi, lo]
// blocks [MPAD, MPAD+768) : weights (kv_w),     layout [hi, lo, hi]
// ---------------------------------------------------------------------------
__global__ __launch_bounds__(192) void pack_both_kernel(
    const float* __restrict__ kvx, const float* __restrict__ kvw,
    __hip_bfloat16* __restrict__ Ab, __hip_bfloat16* __restrict__ Wb)
{
  int b = blockIdx.x, t = threadIdx.x;
  const float* X; __hip_bfloat16* Y; int valid, mode, m;
  if (b < MPAD){ X = kvx; Y = Ab; valid = MKV;     mode = 0; m = b; }
  else         { X = kvw; Y = Wb; valid = D_MODEL; mode = 1; m = b - MPAD; }
  int k = t*4;
  float4 v = (m < valid) ? *(const float4*)&X[(size_t)m*D_MODEL + k]
                         : make_float4(0.f,0.f,0.f,0.f);
  float xsv[4] = {v.x, v.y, v.z, v.w};
  unsigned short hu[4], lu[4];
  #pragma unroll
  for (int i = 0; i < 4; i++){
    __hip_bfloat16 h = __float2bfloat16(xsv[i]);
    float hf = __bfloat162float(h);
    __hip_bfloat16 l = __float2bfloat16(xsv[i] - hf);
    hu[i] = *(unsigned short*)&h;
    lu[i] = *(unsigned short*)&l;
  }
  ushort4 hv = {hu[0], hu[1], hu[2], hu[3]};
  ushort4 lv = {lu[0], lu[1], lu[2], lu[3]};
  ushort4* row = (ushort4*)(Y + (size_t)m*KTOT);
  int s = k >> 2;
  if (mode == 0){ row[s] = hv; row[s+192] = hv; row[s+384] = lv; }
  else          { row[s] = hv; row[s+192] = lv; row[s+384] = hv; }
}

// ---------------------------------------------------------------------------
// bf16 MFMA GEMM: C[kt][m][n] partial over K-split (kt = 0..2).
// 128x128 tile, BK=64, 256 thr = 4 waves (2x2 of 64x64), 16x16x32 MFMA.
// LDS slots xor-swizzled (kg ^= row&7) via per-lane GLOBAL source address.
// ---------------------------------------------------------------------------
__global__ __launch_bounds__(256) void gemm_mfma_kernel(
    const __hip_bfloat16* __restrict__ Ab, const __hip_bfloat16* __restrict__ Wb,
    float* __restrict__ Cp)
{
  __shared__ __hip_bfloat16 As[BM*BK];   // 16 KB
  __shared__ __hip_bfloat16 Bs[BN*BK];   // 16 KB
  int tid = threadIdx.x;
  int wave = tid >> 6, lane = tid & 63;
  int m0 = blockIdx.x*BM, n0 = blockIdx.y*BN, kt = blockIdx.z;
  int wr = wave >> 1, wc = wave & 1;

  float4v acc[4][4];
  #pragma unroll
  for (int i = 0; i < 4; i++)
    #pragma unroll
    for (int j = 0; j < 4; j++)
      acc[i][j] = (float4v){0.f, 0.f, 0.f, 0.f};

  int sbase = wave*256;
  for (int st = 0; st < KPER/BK; ++st){
    int k0 = kt*KPER + st*BK;
    __syncthreads();
    #pragma unroll
    for (int i = 0; i < 4; i++){
      int s  = sbase + i*64 + lane;
      int r  = s >> 3, kg = s & 7;
      int kgg = kg ^ (r & 7);
      gload16(Ab + (size_t)(m0 + r)*KTOT + k0 + kgg*8, (char*)As + (size_t)s*16);
      gload16(Wb + (size_t)(n0 + r)*KTOT + k0 + kgg*8, (char*)Bs + (size_t)s*16);
    }
    __syncthreads();
    #pragma unroll
    for (int ks = 0; ks < 2; ks++){
      int kq = ks*4 + (lane >> 4);
      short8v af[4], bf[4];
      #pragma unroll
      for (int t = 0; t < 4; t++){
        int ar = wr*64 + t*16 + (lane & 15);
        int as_ = ar*8 + (kq ^ (ar & 7));
        af[t] = *(const short8v*)((const char*)As + (size_t)as_*16);
        int br = wc*64 + t*16 + (lane & 15);
        int bs_ = br*8 + (kq ^ (br & 7));
        bf[t] = *(const short8v*)((const char*)Bs + (size_t)bs_*16);
      }
      #pragma unroll
      for (int i = 0; i < 4; i++)
        #pragma unroll
        for (int j = 0; j < 4; j++)
          acc[i][j] = __builtin_amdgcn_mfma_f32_16x16x32_bf16(af[i], bf[j], acc[i][j], 0, 0, 0);
    }
  }

  float* C = Cp + (size_t)kt*MKV*D_MODEL;
  #pragma unroll
  for (int i = 0; i < 4; i++){
    int mb = m0 + wr*64 + i*16 + ((lane >> 4) << 2);
    #pragma unroll
    for (int j = 0; j < 4; j++){
      int n = n0 + wc*64 + j*16 + (lane & 15);
      #pragma unroll
      for (int r = 0; r < 4; r++){
        int m = mb + r;
        if (m < MKV) C[(size_t)m*D_MODEL + n] = acc[i][j][r];
      }
    }
  }
}

// ---------------------------------------------------------------------------
// LN over y0[r]+bias (q path)
// ---------------------------------------------------------------------------
__global__ __launch_bounds__(256) void ln_rows_kernel(
    const float* __restrict__ Y, const float* __restrict__ bias,
    const float* __restrict__ lnw, const float* __restrict__ lnb,
    float* __restrict__ out)
{
  __shared__ float red[256], red2[256];
  int r = blockIdx.x, tid = threadIdx.x;
  const float* yr = Y + (size_t)r*D_MODEL;
  float x0 = yr[tid      ] + bias[tid      ];
  float x1 = yr[tid + 256] + bias[tid + 256];
  float x2 = yr[tid + 512] + bias[tid + 512];
  red[tid] = x0 + x1 + x2; red2[tid] = x0*x0 + x1*x1 + x2*x2;
  __syncthreads();
  for (int st = 128; st > 0; st >>= 1){
    if (tid < st){ red[tid] += red[tid+st]; red2[tid] += red2[tid+st]; }
    __syncthreads();
  }
  float mean = red[0]*(1.f/768.f);
  float var  = red2[0]*(1.f/768.f) - mean*mean;
  float inv  = rsqrtf(var + LN_EPSF);
  float* orow = out + (size_t)r*D_MODEL;
  orow[tid      ] = (x0-mean)*inv*lnw[tid      ] + lnb[tid      ];
  orow[tid + 256] = (x1-mean)*inv*lnw[tid + 256] + lnb[tid + 256];
  orow[tid + 512] = (x2-mean)*inv*lnw[tid + 512] + lnb[tid + 512];
}

// ---------------------------------------------------------------------------
// LN over y0+y1+y2+bias (sums the 3 split-K GEMM partials)
// ---------------------------------------------------------------------------
__global__ __launch_bounds__(256) void ln_rows3_kernel(
    const float* __restrict__ Y0, const float* __restrict__ Y1,
    const float* __restrict__ Y2, const float* __restrict__ bias,
    const float* __restrict__ lnw, const float* __restrict__ lnb,
    float* __restrict__ out)
{
  __shared__ float red[256], red2[256];
  int r = blockIdx.x, tid = threadIdx.x;
  const float* y0 = Y0 + (size_t)r*D_MODEL;
  const float* y1 = Y1 + (size_t)r*D_MODEL;
  const float* y2 = Y2 + (size_t)r*D_MODEL;
  float x0 = y0[tid      ] + y1[tid      ] + y2[tid      ] + bias[tid      ];
  float x1 = y0[tid + 256] + y1[tid + 256] + y2[tid + 256] + bias[tid + 256];
  float x2 = y0[tid + 512] + y1[tid + 512] + y2[tid + 512] + bias[tid + 512];
  red[tid] = x0 + x1 + x2; red2[tid] = x0*x0 + x1*x1 + x2*x2;
  __syncthreads();
  for (int st = 128; st > 0; st >>= 1){
    if (tid < st){ red[tid] += red[tid+st]; red2[tid] += red2[tid+st]; }
    __syncthreads();
  }
  float mean = red[0]*(1.f/768.f);
  float var  = red2[0]*(1.f/768.f) - mean*mean;
  float inv  = rsqrtf(var + LN_EPSF);
  float* orow = out + (size_t)r*D_MODEL;
  orow[tid      ] = (x0-mean)*inv*lnw[tid      ] + lnb[tid      ];
  orow[tid + 256] = (x1-mean)*inv*lnw[tid + 256] + lnb[tid + 256];
  orow[tid + 512] = (x2-mean)*inv*lnw[tid + 512] + lnb[tid + 512];
}

// ---------------------------------------------------------------------------
// Per-(rank, head, half) attention partials.
// ---------------------------------------------------------------------------
__global__ __launch_bounds__(256) void rank_partials_kernel(
    const float* __restrict__ kv_ln, const float* __restrict__ q_ln,
    const float* __restrict__ ppe,
    float* __restrict__ m1O, float* __restrict__ z1O, float* __restrict__ u1O,
    float* __restrict__ m2O, float* __restrict__ z2O, float* __restrict__ u2O)
{
  __shared__ float A[PP*65];
  __shared__ float qs[NQR*64];
  __shared__ float E[NQR*PP];
  int r = blockIdx.x, h = blockIdx.y, half = blockIdx.z;
  int tid = threadIdx.x;

  for (int e = tid; e < NQR*64; e += 256){
    int q = e >> 6, d = e & 63;
    qs[e] = q_ln[q*D_MODEL + h*64 + d];
  }
  for (int e = tid; e < PP*64; e += 256){
    int p = e >> 6, d = e & 63;
    A[p*65 + d] = kv_ln[((size_t)(r*PP + p))*D_MODEL + h*64 + d]
                + ppe[((size_t)(half*PP + p))*D_MODEL + h*64 + d];
  }
  __syncthreads();

  int q = tid >> 5, sub = tid & 31;
  float s[7];
  #pragma unroll
  for (int i = 0; i < 7; i++) s[i] = 0.f;
  for (int d = 0; d < 64; d++){
    float qv = qs[q*64 + d];
    #pragma unroll
    for (int i = 0; i < 7; i++){
      int p = sub + 32*i;
      int pc = p < PP ? p : PP-1;
      s[i] += qv * A[pc*65 + d];
    }
  }
  float mloc = -1e30f;
  #pragma unroll
  for (int i = 0; i < 7; i++){
    int p = sub + 32*i;
    s[i] = (p < PP) ? s[i]*SCALEF : -1e30f;
    mloc = fmaxf(mloc, s[i]);
  }
  for (int off = 16; off >= 1; off >>= 1)
    mloc = fmaxf(mloc, __shfl_xor(mloc, off, 32));
  float zloc = 0.f;
  #pragma unroll
  for (int i = 0; i < 7; i++){
    int p = sub + 32*i;
    float e = __expf(s[i] - mloc);
    if (p < PP){ E[q*PP + p] = e; zloc += e; }
  }
  for (int off = 16; off >= 1; off >>= 1)
    zloc += __shfl_xor(zloc, off, 32);

  int idx = (r*NHEADS + h)*NQR + q;
  float* mO = half ? m2O : m1O;
  float* zO = half ? z2O : z1O;
  float* uO = half ? u2O : u1O;
  if (sub == 0){ mO[idx] = mloc; zO[idx] = zloc; }
  __syncthreads();

  float u0 = 0.f, u1 = 0.f;
  for (int p = 0; p < PP; p++){
    float e = E[q*PP + p];
    u0 += e * A[p*65 + sub];
    u1 += e * A[p*65 + sub + 32];
  }
  uO[(size_t)idx*64 + sub]      = u0;
  uO[(size_t)idx*64 + sub + 32] = u1;
}

// ---------------------------------------------------------------------------
// Rank-partial projection through out_w, per head:
//   P[i,h,q,n] = sum_d U[i,h,q,d] * out_w[n, h*64+d]
// ---------------------------------------------------------------------------
__global__ __launch_bounds__(256) void proj_kernel(
    const float* __restrict__ u1, const float* __restrict__ u2,
    const float* __restrict__ ow, float* __restrict__ p1, float* __restrict__ p2)
{
  __shared__ float Us[128][65];
  __shared__ float Ws[128][65];
  int h = blockIdx.x, n0 = blockIdx.y*128;
  const float* U = blockIdx.z ? u2 : u1;
  float*       P = blockIdx.z ? p2 : p1;
  int tid = threadIdx.x;
  for (int e = tid; e < 128*16; e += 256){
    int m = e >> 4, d4 = (e & 15) << 2;
    int i = m >> 3, q = m & 7;
    float4 v = *(const float4*)&U[(((size_t)i*NHEADS + h)*NQR + q)*64 + d4];
    Us[m][d4] = v.x; Us[m][d4+1] = v.y; Us[m][d4+2] = v.z; Us[m][d4+3] = v.w;
  }
  for (int e = tid; e < 128*16; e += 256){
    int n = e >> 4, d4 = (e & 15) << 2;
    float4 v = *(const float4*)&ow[((size_t)(n0+n))*D_MODEL + h*64 + d4];
    Ws[n][d4] = v.x; Ws[n][d4+1] = v.y; Ws[n][d4+2] = v.z; Ws[n][d4+3] = v.w;
  }
  __syncthreads();
  int tx = tid & 15, ty = tid >> 4;
  float acc[8][8] = {};
  for (int k = 0; k < 64; k++){
    float ur[8], wr[8];
    #pragma unroll
    for (int r = 0; r < 8; r++) ur[r] = Us[ty*8 + r][k];
    #pragma unroll
    for (int c = 0; c < 8; c++) wr[c] = Ws[tx*8 + c][k];
    #pragma unroll
    for (int r = 0; r < 8; r++)
      #pragma unroll
      for (int c = 0; c < 8; c++)
        acc[r][c] += ur[r]*wr[c];
  }
  #pragma unroll
  for (int r = 0; r < 8; r++){
    int m = ty*8 + r, i = m >> 3, q = m & 7;
    float* prow = P + (((size_t)i*NHEADS + h)*NQR + q)*D_MODEL + n0 + tx*8;
    *(float4*)&prow[0] = make_float4(acc[r][0], acc[r][1], acc[r][2], acc[r][3]);
    *(float4*)&prow[4] = make_float4(acc[r][4], acc[r][5], acc[r][6], acc[r][7]);
  }
}

// ---------------------------------------------------------------------------
// Final combine:
//   out[(i*16+j)*8+q, n] = sum_h c1[h]*P1[i,h,q,n] - c2[h]*P2[j,h,q,n] + out_b[n]
// ---------------------------------------------------------------------------
__global__ __launch_bounds__(256) void combine_out_kernel(
    const float* __restrict__ m1, const float* __restrict__ z1,
    const float* __restrict__ m2, const float* __restrict__ z2,
    const float* __restrict__ p1, const float* __restrict__ p2,
    const float* __restrict__ out_b, float* __restrict__ out)
{
  __shared__ float c1s[NHEADS], c2s[NHEADS];
  int pair = blockIdx.x, q = blockIdx.y, tid = threadIdx.x;
  int i = pair >> 4, j = pair & 15;
  if (tid < NHEADS){
    int h = tid;
    int ii = (i*NHEADS + h)*NQR + q;
    int jj = (j*NHEADS + h)*NQR + q;
    float mi = m1[ii], mj = m2[jj];
    float mm = fmaxf(mi, mj);
    float a1 = __expf(mi - mm), a2 = __expf(mj - mm);
    float rden = 1.f / (a1*z1[ii] + a2*z2[jj]);
    c1s[h] = a1*rden; c2s[h] = a2*rden;
  }
  __syncthreads();
  float* orow = out + ((size_t)(pair*NQR + q))*D_MODEL;
  for (int nn = tid; nn < D_MODEL; nn += 256){
    float acc = out_b[nn];
    #pragma unroll
    for (int h = 0; h < NHEADS; h++){
      acc += c1s[h]*p1[(((size_t)i*NHEADS + h)*NQR + q)*D_MODEL + nn]
           - c2s[h]*p2[(((size_t)j*NHEADS + h)*NQR + q)*D_MODEL + nn];
    }
    orow[nn] = acc;
  }
}

// ---------------------------------------------------------------------------
extern "C" void kernel_launch(void* const* d_in, const int* in_sizes, int n_in,
                              void* d_out, int out_size, void* d_ws, size_t ws_size,
                              hipStream_t stream)
{
  const float* q_x    = (const float*)d_in[0];
  const float* kv_x   = (const float*)d_in[1];
  const float* ppe    = (const float*)d_in[2];
  const float* q_w    = (const float*)d_in[3];
  const float* q_b    = (const float*)d_in[4];
  const float* kv_w   = (const float*)d_in[5];
  const float* kv_b   = (const float*)d_in[6];
  const float* out_w  = (const float*)d_in[7];
  const float* out_b  = (const float*)d_in[8];
  const float* lnq_w  = (const float*)d_in[9];
  const float* lnq_b  = (const float*)d_in[10];
  const float* lnkv_w = (const float*)d_in[11];
  const float* lnkv_b = (const float*)d_in[12];
  float* out = (float*)d_out;

  // workspace (f32 units). Aliasing by lifetime:
  //   Abuf (bf16 A', dead after gemm)  <- later kv_ln
  //   Wbuf (bf16 W', dead after gemm)  <- later m/z/u partials
  //   C0..C2 (gemm partials, dead after ln3) <- later p1,p2
  float* ws    = (float*)d_ws;
  float* q_y   = ws;                              //  6144
  float* q_ln  = q_y  + NQR*D_MODEL;              //  6144
  float* Abuf_f = q_ln + NQR*D_MODEL;             //  3,686,400 (3200*2304 bf16)
  float* Wbuf_f = Abuf_f + (size_t)MPAD*KTOT/2;   //    884,736 (768*2304 bf16)
  float* C0    = Wbuf_f + (size_t)D_MODEL*KTOT/2; //  3x 2,420,736
  float* C1    = C0 + (size_t)MKV*D_MODEL;
  float* C2    = C1 + (size_t)MKV*D_MODEL;

  __hip_bfloat16* Abuf = (__hip_bfloat16*)Abuf_f;
  __hip_bfloat16* Wbuf = (__hip_bfloat16*)Wbuf_f;

  float* kv_ln = Abuf_f;                          // alias (2,420,736 <= 3,686,400)
  float* m1    = Wbuf_f;                          // alias region (202,752 <= 884,736)
  float* z1    = m1 + BB*NHEADS*NQR;
  float* m2    = z1 + BB*NHEADS*NQR;
  float* z2    = m2 + BB*NHEADS*NQR;
  float* u1    = z2 + BB*NHEADS*NQR;
  float* u2    = u1 + BB*NHEADS*NQR*DHEAD;
  float* p1    = C0;                              // alias (2,359,296 <= 7,262,208)
  float* p2    = p1 + (size_t)BB*NHEADS*NQR*D_MODEL;

  qgemm_kernel<<<96, 256, 0, stream>>>(q_x, q_w, q_y);
  ln_rows_kernel<<<NQR, 256, 0, stream>>>(q_y, q_b, lnq_w, lnq_b, q_ln);

  pack_both_kernel<<<MPAD + D_MODEL, 192, 0, stream>>>(kv_x, kv_w, Abuf, Wbuf);

  gemm_mfma_kernel<<<dim3(MPAD/BM, D_MODEL/BN, KSPLIT), 256, 0, stream>>>(
      Abuf, Wbuf, C0);

  ln_rows3_kernel<<<MKV, 256, 0, stream>>>(C0, C1, C2, kv_b, lnkv_w, lnkv_b, kv_ln);

  rank_partials_kernel<<<dim3(BB, NHEADS, 2), 256, 0, stream>>>(
      kv_ln, q_ln, ppe, m1, z1, u1, m2, z2, u2);

  proj_kernel<<<dim3(NHEADS, D_MODEL/128, 2), 256, 0, stream>>>(
      u1, u2, out_w, p1, p2);

  combine_out_kernel<<<dim3(NPAIR, NQR), 256, 0, stream>>>(
      m1, z1, m2, z2, p1, p2, out_b, out);
}